// Round 1
// baseline (93.956 us; speedup 1.0000x reference)
//
#include <hip/hip_runtime.h>
#include <hip/hip_bf16.h>
#include <stdint.h>

#define M_DIM 32
#define K_DIM 8192
#define N_DIM 8192
#define NGROUPS 64
#define KSPLIT 8
#define KPART (K_DIM / KSPLIT)     // 1024 k per part
#define GPART (NGROUPS / KSPLIT)   // 8 groups per part
#define BN 64
#define NPH 4                      // phases per part: 256 k (2 groups) each

#define QSTRIDE 72   // dwords per q-row in LDS (64+8): b32 frag reads 2-way = free
#define ASTRIDE 132  // dwords per A-phase-row (128+4): 16B-aligned, b128 ops balanced

typedef __attribute__((ext_vector_type(8))) short short8;   // 8 bf16 (4 VGPRs)
typedef __attribute__((ext_vector_type(4))) float floatx4;  // MFMA acc

// ---------------------------------------------------------------------------
// Prep: A (fp32, 32x8192) -> Abf (bf16, octet-permuted [0,4,1,5,2,6,3,7]) and
// R[m][g] = per-group sum of bf16-ROUNDED A (cancels the +128 nibble offset:
// A*(q+128) - 136*R == A*(q-8) exactly).  R6: no out-zeroing (no atomics now).
// ---------------------------------------------------------------------------
__global__ void marlin_prep_kernel(const float* __restrict__ A,
                                   uint16_t* __restrict__ Abf,
                                   float* __restrict__ R) {
    const int m = blockIdx.x;
    const int qtr = blockIdx.y;
    const int t = threadIdx.x;
    const int octet = qtr * 256 + t;     // 0..1023
    const int k0 = octet * 8;

    const float* a = A + m * K_DIM + k0;
    uint16_t b[8];
    float sum = 0.f;
#pragma unroll
    for (int j = 0; j < 8; j++) {
        union { __hip_bfloat16 h; uint16_t u; } cv;
        cv.h = __float2bfloat16(a[j]);   // round-to-nearest bf16
        b[j] = cv.u;
        sum += __bfloat162float(cv.h);   // sum of the ROUNDED values
    }
    // pack in permuted k-order [0,4,1,5,2,6,3,7] to match nibble-pair extract
    uint32_t w0 = (uint32_t)b[0] | ((uint32_t)b[4] << 16);
    uint32_t w1 = (uint32_t)b[1] | ((uint32_t)b[5] << 16);
    uint32_t w2 = (uint32_t)b[2] | ((uint32_t)b[6] << 16);
    uint32_t w3 = (uint32_t)b[3] | ((uint32_t)b[7] << 16);
    *(uint4*)(Abf + (size_t)m * K_DIM + k0) = make_uint4(w0, w1, w2, w3);

#pragma unroll
    for (int off = 1; off < 16; off <<= 1) sum += __shfl_xor(sum, off, 16);
    if ((t & 15) == 0) R[m * NGROUPS + qtr * 16 + (t >> 4)] = sum;
}

// ---------------------------------------------------------------------------
// Main R6: grid (N/64, KSPLIT=8) x 512 threads (8 waves = 2 mtile x 4 ntile).
// R5 post-mortem: __syncthreads() forces s_waitcnt vmcnt(0) -> every group
// iteration pays full HBM latency serialized (prefetch killed at barrier), and
// 2M fp32 atomicAdds (8-way cross-XCD same-address) dominate the tail.
// R6: (a) counted-wait barrier: ds_write staging -> asm lgkmcnt(0) -> raw
// s_barrier; global prefetch loads STAY IN FLIGHT across the barrier (T3/T4),
// (b) 2-group phases (4 barriers instead of 8, uint4 staging loads),
// (c) NO atomics: per-bz partials to workspace + tiny reduce kernel.
// Double-buffer + 1 barrier/phase is race-free: a wave writing buf[p&1] has
// passed barrier(p-1), so all waves finished compute(p-2); the only concurrent
// readers use buf[(p-1)&1].
// ---------------------------------------------------------------------------
__global__ __launch_bounds__(512, 4) void
MarlinQuantLinear_68556267979256_kernel(const int* __restrict__ qw,
                                        const float* __restrict__ scales,
                                        const uint16_t* __restrict__ Abf,
                                        const float* __restrict__ R,
                                        float* __restrict__ parts) {
    __shared__ uint32_t qbuf[2][32 * QSTRIDE];   // 18432 B
    __shared__ uint32_t abuf[2][32 * ASTRIDE];   // 33792 B
    __shared__ float    r_lds[32 * 9];           //  1152 B  (~52 KB total)

    const int bx = blockIdx.x;           // n-tile block
    const int bz = blockIdx.y;           // k-split part
    const int nbase = bx * BN;
    const int gbase = bz * GPART;

    const int tid = threadIdx.x;
    const int w = tid >> 6;
    const int lane = tid & 63;
    const int quad = lane >> 4;
    const int l16 = lane & 15;
    const int mtile = w & 1;
    const int ntile = w >> 1;
    const int ncol = nbase + ntile * 16 + l16;

    // ---- coalesced staging maps: row = tid>>4 (0..31), contiguous segments
    const int sr = tid >> 4;
    const int sc = (tid & 15) * 4;       // q: 16B per thread per phase
    const int ac = (tid & 15) * 8;       // A: 32B per thread per phase
    const int* qsrc = qw + (size_t)(bz * 128 + sr) * N_DIM + nbase + sc;
    const uint32_t* asrc = (const uint32_t*)Abf + (size_t)sr * (K_DIM / 2)
                           + bz * (KPART / 2) + ac;

    // initial tile (phase 0) — issued FIRST so later waits are counted
    uint4 qst = *(const uint4*)qsrc;
    uint4 a0  = *(const uint4*)asrc;
    uint4 a1  = *(const uint4*)(asrc + 4);

    // scale prefetch (in flight during first stage, consumed at epilogues)
    const float* scol = scales + (size_t)gbase * N_DIM + ncol;
    float s[GPART];
#pragma unroll
    for (int g = 0; g < GPART; g++) s[g] = scol[g * N_DIM];

    // one-time stage of this part's R (prescaled by 136): 32m x 8g
    if (tid < 256) {
        const int mm = tid >> 3, gg = tid & 7;
        r_lds[mm * 9 + gg] = 136.0f * R[mm * NGROUPS + gbase + gg];
    }

    floatx4 C = {0.f, 0.f, 0.f, 0.f};

#pragma unroll
    for (int p = 0; p < NPH; p++) {
        // stage current tile (compiler emits counted vmcnt for these regs;
        // newer prefetch loads remain outstanding)
        *(uint4*)&qbuf[p & 1][sr * QSTRIDE + sc] = qst;
        *(uint4*)&abuf[p & 1][sr * ASTRIDE + ac] = a0;
        *(uint4*)&abuf[p & 1][sr * ASTRIDE + ac + 4] = a1;
        // order ONLY the LDS writes before the barrier — no vmcnt drain
        asm volatile("s_waitcnt lgkmcnt(0)" ::: "memory");
        __builtin_amdgcn_s_barrier();

        // issue next phase's loads now: a full compute phase hides the latency
        if (p + 1 < NPH) {
            qst = *(const uint4*)(qsrc + (size_t)(p + 1) * 32 * N_DIM);
            a0  = *(const uint4*)(asrc + (p + 1) * 128);
            a1  = *(const uint4*)(asrc + (p + 1) * 128 + 4);
        }

#pragma unroll
        for (int gg = 0; gg < 2; gg++) {
            floatx4 accg = {0.f, 0.f, 0.f, 0.f};
#pragma unroll
            for (int t = 0; t < 4; t++) {
                const uint32_t q =
                    qbuf[p & 1][(gg * 16 + t * 4 + quad) * QSTRIDE + ntile * 16 + l16];
                union { uint32_t u[4]; short8 v; } fb;
                fb.u[0] = ( q        & 0x000F000Fu) | 0x43004300u;  // k0,k4
                fb.u[1] = ((q >> 4)  & 0x000F000Fu) | 0x43004300u;  // k1,k5
                fb.u[2] = ((q >> 8)  & 0x000F000Fu) | 0x43004300u;  // k2,k6
                fb.u[3] = ((q >> 12) & 0x000F000Fu) | 0x43004300u;  // k3,k7
                const short8 fa = *(const short8*)
                    &abuf[p & 1][(mtile * 16 + l16) * ASTRIDE + gg * 64 + t * 16 + quad * 4];
                accg = __builtin_amdgcn_mfma_f32_16x16x32_bf16(fa, fb.v, accg, 0, 0, 0);
            }
            const int g = p * 2 + gg;
#pragma unroll
            for (int r = 0; r < 4; r++) {
                const float tval = accg[r] - r_lds[(mtile * 16 + quad * 4 + r) * 9 + g];
                C[r] = fmaf(s[g], tval, C[r]);
            }
        }
    }

    // fire-and-forget partial stores (no atomics, no RMW, no zeroing needed)
    float* pp = parts + ((size_t)bz * M_DIM + mtile * 16 + quad * 4) * N_DIM + ncol;
#pragma unroll
    for (int r = 0; r < 4; r++) pp[r * N_DIM] = C[r];
}

// ---------------------------------------------------------------------------
// Reduce: out[m][n] = sum_bz parts[bz][m][n] + bias[n].  9 MB traffic ~2-3 us.
// ---------------------------------------------------------------------------
__global__ __launch_bounds__(256) void
marlin_reduce_kernel(const float* __restrict__ parts,
                     const float* __restrict__ bias,
                     float* __restrict__ out) {
    const int idx = blockIdx.x * 256 + threadIdx.x;   // 0..65535 float4s
    const int c4 = idx & (N_DIM / 4 - 1);
    const float4* p4 = (const float4*)parts;
    float4 acc = *(const float4*)(bias + c4 * 4);
#pragma unroll
    for (int bz = 0; bz < KSPLIT; bz++) {
        const float4 v = p4[(size_t)bz * (M_DIM * N_DIM / 4) + idx];
        acc.x += v.x; acc.y += v.y; acc.z += v.z; acc.w += v.w;
    }
    ((float4*)out)[idx] = acc;
}

extern "C" void kernel_launch(void* const* d_in, const int* in_sizes, int n_in,
                              void* d_out, int out_size, void* d_ws, size_t ws_size,
                              hipStream_t stream) {
    const float* A      = (const float*)d_in[0];
    const int*   qw     = (const int*)d_in[1];
    const float* scales = (const float*)d_in[2];
    const float* bias   = (const float*)d_in[3];
    float* out = (float*)d_out;

    uint16_t* Abf   = (uint16_t*)d_ws;                                   // 512 KB
    float*    R     = (float*)((char*)d_ws + (size_t)M_DIM * K_DIM * 2); //   8 KB
    float*    parts = (float*)((char*)d_ws + (1 << 20));                 //   8 MB

    marlin_prep_kernel<<<dim3(M_DIM, 4), 256, 0, stream>>>(A, Abf, R);
    MarlinQuantLinear_68556267979256_kernel<<<dim3(N_DIM / BN, KSPLIT), 512, 0, stream>>>(
        qw, scales, Abf, R, parts);
    marlin_reduce_kernel<<<dim3((M_DIM * N_DIM / 4) / 256), 256, 0, stream>>>(
        parts, bias, out);
}

// Round 2
// 91.001 us; speedup vs baseline: 1.0325x; 1.0325x over previous
//
#include <hip/hip_runtime.h>
#include <hip/hip_bf16.h>
#include <stdint.h>

#define M_DIM 32
#define K_DIM 8192
#define N_DIM 8192
#define NGROUPS 64
#define KSPLIT 8
#define KPART (K_DIM / KSPLIT)     // 1024 k per part
#define GPART (NGROUPS / KSPLIT)   // 8 groups per part = 8 phases
#define BN 256                     // R7: 4x wider n-panel -> 1KB/row q segments

#define QSTRIDE 264  // dwords per q-LDS row (256+8): frag b32 reads 2-way = free
#define ASTRIDE 68   // dwords per A-phase-row (64+4): b128 frag reads balanced
#define SSTRIDE 260  // dwords per scales-LDS row

typedef __attribute__((ext_vector_type(8))) short short8;   // 8 bf16 (4 VGPRs)
typedef __attribute__((ext_vector_type(4))) float floatx4;  // MFMA acc

// ---------------------------------------------------------------------------
// Prep: A (fp32, 32x8192) -> Abf (bf16, octet-permuted [0,4,1,5,2,6,3,7]) and
// R[m][g] = per-group sum of bf16-ROUNDED A (cancels the +128 nibble offset:
// A*(q+128) - 136*R == A*(q-8) exactly).
// ---------------------------------------------------------------------------
__global__ void marlin_prep_kernel(const float* __restrict__ A,
                                   uint16_t* __restrict__ Abf,
                                   float* __restrict__ R) {
    const int m = blockIdx.x;
    const int qtr = blockIdx.y;
    const int t = threadIdx.x;
    const int octet = qtr * 256 + t;     // 0..1023
    const int k0 = octet * 8;

    const float* a = A + m * K_DIM + k0;
    uint16_t b[8];
    float sum = 0.f;
#pragma unroll
    for (int j = 0; j < 8; j++) {
        union { __hip_bfloat16 h; uint16_t u; } cv;
        cv.h = __float2bfloat16(a[j]);   // round-to-nearest bf16
        b[j] = cv.u;
        sum += __bfloat162float(cv.h);   // sum of the ROUNDED values
    }
    uint32_t w0 = (uint32_t)b[0] | ((uint32_t)b[4] << 16);
    uint32_t w1 = (uint32_t)b[1] | ((uint32_t)b[5] << 16);
    uint32_t w2 = (uint32_t)b[2] | ((uint32_t)b[6] << 16);
    uint32_t w3 = (uint32_t)b[3] | ((uint32_t)b[7] << 16);
    *(uint4*)(Abf + (size_t)m * K_DIM + k0) = make_uint4(w0, w1, w2, w3);

#pragma unroll
    for (int off = 1; off < 16; off <<= 1) sum += __shfl_xor(sum, off, 16);
    if ((t & 15) == 0) R[m * NGROUPS + qtr * 16 + (t >> 4)] = sum;
}

// ---------------------------------------------------------------------------
// Main R7: grid (KSPLIT=8, N/256=32) x 512 threads (8 waves = 2 mtile x 4 ntile).
// R6 post-mortem: counted-wait + atomics-removal both NEUTRAL at ~42us; the
// kernel moves 42MB at ~1TB/s -> DRAM page/activate-bound on 256B-per-row
// scattered q segments (R4's "~520GB/s regardless of prefetch" in new clothes).
// R7: BN=256 -> 1KB contiguous per q-row per block; blockIdx.x=bz -> XCD owns
// a contiguous 4MB q slab, its 32 co-started blocks read adjacent 1KB column
// segments of the same rows concurrently (page-sequential DRAM traffic) and
// share the 64KB A-part in XCD L2.  A-fragments now reused across 4 n-frags.
// ---------------------------------------------------------------------------
__global__ __launch_bounds__(512, 2) void
MarlinQuantLinear_68556267979256_kernel(const int* __restrict__ qw,
                                        const float* __restrict__ scales,
                                        const uint16_t* __restrict__ Abf,
                                        const float* __restrict__ R,
                                        float* __restrict__ parts) {
    __shared__ uint32_t qbuf[2][16 * QSTRIDE];   // 33792 B
    __shared__ uint32_t abuf[2][32 * ASTRIDE];   // 17408 B
    __shared__ float    s_lds[GPART * SSTRIDE];  //  8320 B
    __shared__ float    r_lds[32 * 9];           //  1152 B  (~60 KB total)

    const int bz = blockIdx.x;           // k-split part == XCD id (linear%8)
    const int bx = blockIdx.y;           // n panel
    const int nbase = bx * BN;
    const int gbase = bz * GPART;

    const int tid = threadIdx.x;
    const int w = tid >> 6;
    const int lane = tid & 63;
    const int quad = lane >> 4;
    const int l16 = lane & 15;
    const int mtile = w & 1;             // m rows [mtile*16, +16)
    const int ntile = w >> 1;            // n cols [ntile*64, +64) within panel

    // ---- coalesced staging maps ----
    // q: row qr 0..15 (group-local), two contiguous 512B half-rows per wave
    const int qr = tid >> 5;
    const int qc = (tid & 31) * 4;       // dword col; second load at +128
    const int* qsrc = qw + (size_t)(bz * 128 + qr) * N_DIM + nbase + qc;
    // A: row ar 0..31, 16B per thread (64 dwords = 128k per phase-row)
    const int ar = tid >> 4;
    const int ac = (tid & 15) * 4;
    const uint32_t* asrc = (const uint32_t*)Abf + (size_t)ar * (K_DIM / 2)
                           + bz * (KPART / 2) + ac;

    // initial tile (g=0) issued before one-time stages
    uint4 q0 = *(const uint4*)qsrc;
    uint4 q1 = *(const uint4*)(qsrc + 128);
    uint4 a0 = *(const uint4*)asrc;

    // one-time cooperative stages: scales (8 groups x 256 cols) and 136*R
    {
        const int sg = tid >> 6, scc = (tid & 63) * 4;
        const float4 sv = *(const float4*)(scales + (size_t)(gbase + sg) * N_DIM
                                           + nbase + scc);
        *(float4*)&s_lds[sg * SSTRIDE + scc] = sv;
    }
    if (tid < 256) {
        const int mm = tid >> 3, gg = tid & 7;
        r_lds[mm * 9 + gg] = 136.0f * R[mm * NGROUPS + gbase + gg];
    }

    floatx4 C[4] = {{0.f, 0.f, 0.f, 0.f}, {0.f, 0.f, 0.f, 0.f},
                    {0.f, 0.f, 0.f, 0.f}, {0.f, 0.f, 0.f, 0.f}};

#pragma unroll
    for (int g = 0; g < GPART; g++) {
        // stage current tile; counted vmcnt only for these regs
        *(uint4*)&qbuf[g & 1][qr * QSTRIDE + qc] = q0;
        *(uint4*)&qbuf[g & 1][qr * QSTRIDE + qc + 128] = q1;
        *(uint4*)&abuf[g & 1][ar * ASTRIDE + ac] = a0;
        // order ONLY the LDS writes before the barrier — no vmcnt drain
        asm volatile("s_waitcnt lgkmcnt(0)" ::: "memory");
        __builtin_amdgcn_s_barrier();

        // issue next phase's loads; a full compute phase hides the latency
        if (g + 1 < GPART) {
            q0 = *(const uint4*)(qsrc + (size_t)(g + 1) * 16 * N_DIM);
            q1 = *(const uint4*)(qsrc + (size_t)(g + 1) * 16 * N_DIM + 128);
            a0 = *(const uint4*)(asrc + (g + 1) * 64);
        }

        floatx4 accg[4] = {{0.f, 0.f, 0.f, 0.f}, {0.f, 0.f, 0.f, 0.f},
                           {0.f, 0.f, 0.f, 0.f}, {0.f, 0.f, 0.f, 0.f}};
#pragma unroll
        for (int t = 0; t < 4; t++) {
            // A fragment: one b128, REUSED across the 4 n-fragments
            const short8 fa = *(const short8*)
                &abuf[g & 1][(mtile * 16 + l16) * ASTRIDE + t * 16 + quad * 4];
#pragma unroll
            for (int f = 0; f < 4; f++) {
                const uint32_t q =
                    qbuf[g & 1][(t * 4 + quad) * QSTRIDE + ntile * 64 + f * 16 + l16];
                union { uint32_t u[4]; short8 v; } fb;
                fb.u[0] = ( q        & 0x000F000Fu) | 0x43004300u;  // k0,k4
                fb.u[1] = ((q >> 4)  & 0x000F000Fu) | 0x43004300u;  // k1,k5
                fb.u[2] = ((q >> 8)  & 0x000F000Fu) | 0x43004300u;  // k2,k6
                fb.u[3] = ((q >> 12) & 0x000F000Fu) | 0x43004300u;  // k3,k7
                accg[f] = __builtin_amdgcn_mfma_f32_16x16x32_bf16(fa, fb.v, accg[f], 0, 0, 0);
            }
        }
#pragma unroll
        for (int f = 0; f < 4; f++) {
            const float sv = s_lds[g * SSTRIDE + ntile * 64 + f * 16 + l16];
#pragma unroll
            for (int r = 0; r < 4; r++) {
                const float tval = accg[f][r] - r_lds[(mtile * 16 + quad * 4 + r) * 9 + g];
                C[f][r] = fmaf(sv, tval, C[f][r]);
            }
        }
    }

    // fire-and-forget partial stores
#pragma unroll
    for (int f = 0; f < 4; f++) {
        const int ncol = nbase + ntile * 64 + f * 16 + l16;
        float* pp = parts + ((size_t)bz * M_DIM + mtile * 16 + quad * 4) * N_DIM + ncol;
#pragma unroll
        for (int r = 0; r < 4; r++) pp[r * N_DIM] = C[f][r];
    }
}

// ---------------------------------------------------------------------------
// Reduce: out[m][n] = sum_bz parts[bz][m][n] + bias[n].  9 MB traffic.
// ---------------------------------------------------------------------------
__global__ __launch_bounds__(256) void
marlin_reduce_kernel(const float* __restrict__ parts,
                     const float* __restrict__ bias,
                     float* __restrict__ out) {
    const int idx = blockIdx.x * 256 + threadIdx.x;   // 0..65535 float4s
    const int c4 = idx & (N_DIM / 4 - 1);
    const float4* p4 = (const float4*)parts;
    float4 acc = *(const float4*)(bias + c4 * 4);
#pragma unroll
    for (int bz = 0; bz < KSPLIT; bz++) {
        const float4 v = p4[(size_t)bz * (M_DIM * N_DIM / 4) + idx];
        acc.x += v.x; acc.y += v.y; acc.z += v.z; acc.w += v.w;
    }
    ((float4*)out)[idx] = acc;
}

extern "C" void kernel_launch(void* const* d_in, const int* in_sizes, int n_in,
                              void* d_out, int out_size, void* d_ws, size_t ws_size,
                              hipStream_t stream) {
    const float* A      = (const float*)d_in[0];
    const int*   qw     = (const int*)d_in[1];
    const float* scales = (const float*)d_in[2];
    const float* bias   = (const float*)d_in[3];
    float* out = (float*)d_out;

    uint16_t* Abf   = (uint16_t*)d_ws;                                   // 512 KB
    float*    R     = (float*)((char*)d_ws + (size_t)M_DIM * K_DIM * 2); //   8 KB
    float*    parts = (float*)((char*)d_ws + (1 << 20));                 //   8 MB

    marlin_prep_kernel<<<dim3(M_DIM, 4), 256, 0, stream>>>(A, Abf, R);
    MarlinQuantLinear_68556267979256_kernel<<<dim3(KSPLIT, N_DIM / BN), 512, 0, stream>>>(
        qw, scales, Abf, R, parts);
    marlin_reduce_kernel<<<dim3((M_DIM * N_DIM / 4) / 256), 256, 0, stream>>>(
        parts, bias, out);
}